// Round 4
// baseline (199.892 us; speedup 1.0000x reference)
//
#include <hip/hip_runtime.h>

// CrossWarpingModule: 4-phase pixel-unshuffle -> axial attention (8 heads, c=1)
// -> flow -> bilinear border grid_sample -> pixel-shuffle back.
// B=2, C=64, H=W=256; sub-images: 8 x [64][128][128].
//
// R4: warp rewritten output-major (coalesced stores, phase from (Y&1,X&1));
// qkv 4-way channel split + LDS tree reduce (32 waves/CU, 16-load chain);
// both attn passes fused into one 2048-block launch.

constexpr int PLANE = 16384;                 // 128*128
constexpr float LOG2E = 1.4426950408889634f;

// ---------------------------------------------------------------------------
// Kernel 1: q/k/v projection. Block = (b, Y, X-half): 128 contiguous X
// positions x 4 channel-groups (16 ch each). Tree-reduce in LDS.
// grid 1024 x 512.
// ---------------------------------------------------------------------------
__global__ __launch_bounds__(512) void qkv_kernel(
    const float* __restrict__ cur, const float* __restrict__ ref,
    const float* __restrict__ Wq, const float* __restrict__ Wk,
    const float* __restrict__ Wv,
    float* __restrict__ Q, float* __restrict__ K, float* __restrict__ V)
{
    __shared__ float WT[64 * 24];       // WT[c][j]: j<8 Wq, <16 Wk, <24 Wv
    __shared__ float red0[128 * 25];    // stride 25: conflict-free
    __shared__ float red1[128 * 25];
    const int tid = threadIdx.x;
    for (int i = tid; i < 64 * 24; i += 512) {
        int c = i / 24, j = i % 24;
        float val = (j < 8) ? Wq[j * 64 + c]
                  : (j < 16) ? Wk[(j - 8) * 64 + c]
                  : Wv[(j - 16) * 64 + c];
        WT[c * 24 + j] = val;
    }
    __syncthreads();

    const int bi = blockIdx.x;               // 0..1023
    const int b  = bi >> 9;                  // batch
    const int Y  = (bi >> 1) & 255;          // full-res row
    const int Xh = bi & 1;                   // X half
    const int cg = tid >> 7;                 // channel group 0..3
    const int xi = tid & 127;
    const int X  = Xh * 128 + xi;            // full-res col (contiguous/lane)

    const size_t base_in = (size_t)b * 64 * 65536 + (size_t)Y * 256 + X;
    const float* curp = cur + base_in;
    const float* refp = ref + base_in;

    float q[8], k[8], v[8];
#pragma unroll
    for (int i = 0; i < 8; ++i) { q[i] = 0.f; k[i] = 0.f; v[i] = 0.f; }

    const int c0 = cg * 16;
#pragma unroll 8
    for (int c = 0; c < 16; ++c) {
        float cu = curp[(size_t)(c0 + c) * 65536];
        float rf = refp[(size_t)(c0 + c) * 65536];
        const float* wr = &WT[(c0 + c) * 24];
#pragma unroll
        for (int i = 0; i < 8; ++i) {
            q[i] = fmaf(wr[i],      cu, q[i]);
            k[i] = fmaf(wr[8 + i],  rf, k[i]);
            v[i] = fmaf(wr[16 + i], rf, v[i]);
        }
    }

    // tree reduce: (1 -> red0), (3 -> red1); (2 += red1 -> red1); (0 += red0,red1)
    float* row0 = &red0[xi * 25];
    float* row1 = &red1[xi * 25];
    if (cg == 1) {
#pragma unroll
        for (int i = 0; i < 8; ++i) {
            row0[i] = q[i]; row0[8 + i] = k[i]; row0[16 + i] = v[i];
        }
    } else if (cg == 3) {
#pragma unroll
        for (int i = 0; i < 8; ++i) {
            row1[i] = q[i]; row1[8 + i] = k[i]; row1[16 + i] = v[i];
        }
    }
    __syncthreads();
    if (cg == 2) {
#pragma unroll
        for (int i = 0; i < 8; ++i) {
            row1[i]      += q[i];
            row1[8 + i]  += k[i];
            row1[16 + i] += v[i];
        }
    } else if (cg == 0) {
#pragma unroll
        for (int i = 0; i < 8; ++i) {
            q[i] += row0[i]; k[i] += row0[8 + i]; v[i] += row0[16 + i];
        }
    }
    __syncthreads();
    if (cg == 0) {
        const int dy = Y & 1, dx = X & 1;
        // (dy,dx)->phase: (0,0)=0 (1,1)=1 (0,1)=2 (1,0)=3
        const int p  = dy ? (dx ? 1 : 3) : (dx ? 2 : 0);
        const int sb = p * 2 + b;
        const int h = Y >> 1, w = X >> 1;
#pragma unroll
        for (int i = 0; i < 8; ++i) {
            const size_t o = ((size_t)(sb * 8 + i) << 14) + (h << 7) + w;
            Q[o] = q[i] + row1[i];
            K[o] = k[i] + row1[8 + i];
            V[o] = v[i] + row1[16 + i];
        }
    }
}

// ---------------------------------------------------------------------------
// Kernel 2: per-plane 128x128 transpose of Q,K,V -> QT,KT,VT. 32x32 LDS
// tiles, coalesced float4 on both sides. grid 1024 x 256.
// ---------------------------------------------------------------------------
__global__ __launch_bounds__(256) void transpose_kernel(
    const float* __restrict__ Q, const float* __restrict__ K,
    const float* __restrict__ V,
    float* __restrict__ QT, float* __restrict__ KT, float* __restrict__ VT)
{
    __shared__ float tile[32 * 33];
    const int bi = blockIdx.x;         // 0..1023
    const int plane = bi >> 4;         // (sb*8+head)
    const int ti = (bi >> 2) & 3, tj = bi & 3;
    const int t = threadIdx.x;
    const int r = t >> 3, c4 = (t & 7) * 4;     // 32 rows x 8 float4 cols
    const size_t pb = (size_t)plane << 14;
    const size_t ibase = pb + (size_t)(ti * 32) * 128 + tj * 32;
    const size_t obase = pb + (size_t)(tj * 32) * 128 + ti * 32;

    const float* srcs[3] = { Q, K, V };
    float* dsts[3] = { QT, KT, VT };
#pragma unroll
    for (int a = 0; a < 3; ++a) {
        const float* src = srcs[a];
        float* dst = dsts[a];
        const float4 val = *(const float4*)&src[ibase + (size_t)r * 128 + c4];
        if (a) __syncthreads();
        tile[r * 33 + c4 + 0] = val.x;
        tile[r * 33 + c4 + 1] = val.y;
        tile[r * 33 + c4 + 2] = val.z;
        tile[r * 33 + c4 + 3] = val.w;
        __syncthreads();
        float4 o;
        o.x = tile[(c4 + 0) * 33 + r];
        o.y = tile[(c4 + 1) * 33 + r];
        o.z = tile[(c4 + 2) * 33 + r];
        o.w = tile[(c4 + 3) * 33 + r];
        *(float4*)&dst[obase + (size_t)r * 128 + c4] = o;
    }
}

// ---------------------------------------------------------------------------
// Kernel 3: both axial attention passes + 8->1 head projection, fused.
// Block 0..1023:   horizontal (Q,K,V, Whor) -> OH[sb][h][w]   (line=h, t=w)
// Block 1024..2047: vertical  (QT,KT,VT,Wver) -> OVT[sb][w][h] (line=w, t=h)
// 1024 threads = (head = tid>>7 wave-uniform, t = tid&127); k (pre-scaled by
// log2e) and v in LDS -> broadcast ds_read_b128; 4 accumulator pairs for ILP.
// No max-subtract: |q·k| <~ 6, far inside exp2 range (matches ref, fp32).
// grid 2048 x 1024.
// ---------------------------------------------------------------------------
__global__ __launch_bounds__(1024) void attn_fused(
    const float* __restrict__ Q, const float* __restrict__ K,
    const float* __restrict__ V,
    const float* __restrict__ QT, const float* __restrict__ KT,
    const float* __restrict__ VT,
    const float* __restrict__ Whor, const float* __restrict__ Wver,
    float* __restrict__ OH, float* __restrict__ OVT)
{
    __shared__ float kk[8 * 128];   // [head][l], pre-scaled by log2(e)
    __shared__ float vv[8 * 128];
    __shared__ float red[8 * 128];  // per-head softmax-weighted sums

    const int pass = blockIdx.x >> 10;
    const float* __restrict__ Qa = pass ? QT : Q;
    const float* __restrict__ Ka = pass ? KT : K;
    const float* __restrict__ Va = pass ? VT : V;
    const float* __restrict__ wsel = pass ? Wver : Whor;
    float* __restrict__ o = pass ? OVT : OH;

    const int tid  = threadIdx.x;
    const int head = tid >> 7;
    const int t    = tid & 127;
    const int sbl  = blockIdx.x & 1023;
    const int sb   = sbl >> 7;
    const int line = sbl & 127;

    const size_t row = (((size_t)(sb * 8 + head)) << 14) + ((size_t)line << 7);
    kk[tid] = LOG2E * Ka[row + t];
    vv[tid] = Va[row + t];
    const float s = Qa[row + t];
    __syncthreads();

    const float4* k4 = (const float4*)&kk[head << 7];
    const float4* v4 = (const float4*)&vv[head << 7];
    float d0 = 0.f, d1 = 0.f, d2 = 0.f, d3 = 0.f;
    float n0 = 0.f, n1 = 0.f, n2 = 0.f, n3 = 0.f;
#pragma unroll 8
    for (int l = 0; l < 32; ++l) {
        const float4 kq = k4[l];
        const float4 vq = v4[l];
        const float e0 = __builtin_amdgcn_exp2f(s * kq.x);
        const float e1 = __builtin_amdgcn_exp2f(s * kq.y);
        const float e2 = __builtin_amdgcn_exp2f(s * kq.z);
        const float e3 = __builtin_amdgcn_exp2f(s * kq.w);
        d0 += e0; n0 = fmaf(e0, vq.x, n0);
        d1 += e1; n1 = fmaf(e1, vq.y, n1);
        d2 += e2; n2 = fmaf(e2, vq.z, n2);
        d3 += e3; n3 = fmaf(e3, vq.w, n3);
    }
    const float den = (d0 + d1) + (d2 + d3);
    const float num = (n0 + n1) + (n2 + n3);
    red[tid] = num * __builtin_amdgcn_rcpf(den);
    __syncthreads();

    if (tid < 128) {
        float acc = 0.f;
#pragma unroll
        for (int i = 0; i < 8; ++i)
            acc = fmaf(wsel[i], red[(i << 7) + tid], acc);
        o[((size_t)sb << 14) + ((size_t)line << 7) + tid] = acc;
    }
}

// ---------------------------------------------------------------------------
// Kernel 4: warp, output-major. Block = (b, cgroup, Y); lane = X. Phase from
// (Y&1, X&1) => stores are contiguous full-res rows (fully coalesced); the
// even/odd-lane union makes bilinear gathers near-contiguous (col ~ X+2*flow).
// Flow read once per pixel, reused over 16 channels. grid 2048 x 256.
// ---------------------------------------------------------------------------
__global__ __launch_bounds__(256) void warp_kernel(
    const float* __restrict__ ref, const float* __restrict__ ovt,
    const float* __restrict__ oh, float* __restrict__ out)
{
    const int bi = blockIdx.x;          // 0..2047
    const int Y  = bi & 255;
    const int cg = (bi >> 8) & 3;
    const int b  = bi >> 10;
    const int X  = threadIdx.x;

    const int dy = Y & 1, dx = X & 1;
    const int p  = dy ? (dx ? 1 : 3) : (dx ? 2 : 0);
    const int sb = p * 2 + b;
    const int h = Y >> 1, w = X >> 1;

    // normalized-coord round trip cancels exactly:
    const float ix = (float)w + oh [((size_t)sb << 14) + (h << 7) + w];
    const float iy = (float)h + ovt[((size_t)sb << 14) + (w << 7) + h];

    const float x0f = floorf(ix), y0f = floorf(iy);
    const float wx = ix - x0f,    wy = iy - y0f;
    const int x0 = (int)x0f, y0 = (int)y0f;
    const int x0c = min(max(x0, 0), 127),     x1c = min(max(x0 + 1, 0), 127);
    const int y0c = min(max(y0, 0), 127),     y1c = min(max(y0 + 1, 0), 127);

    const float w00 = (1.f - wx) * (1.f - wy);
    const float w01 = wx * (1.f - wy);
    const float w10 = (1.f - wx) * wy;
    const float w11 = wx * wy;

    const int r0 = (2 * y0c + dy) * 256, r1 = (2 * y1c + dy) * 256;
    const int c0 = 2 * x0c + dx,         c1 = 2 * x1c + dx;
    const int o00 = r0 + c0, o01 = r0 + c1, o10 = r1 + c0, o11 = r1 + c1;
    const int dst = Y * 256 + X;

    const float* rp = ref + ((size_t)b * 64 + cg * 16) * 65536;
    float* op = out + ((size_t)b * 64 + cg * 16) * 65536;

#pragma unroll 4
    for (int c = 0; c < 16; ++c) {
        const size_t pl = (size_t)c * 65536;
        const float v00 = rp[pl + o00], v01 = rp[pl + o01];
        const float v10 = rp[pl + o10], v11 = rp[pl + o11];
        op[pl + dst] = fmaf(w00, v00, fmaf(w01, v01, fmaf(w10, v10, w11 * v11)));
    }
}

// ---------------------------------------------------------------------------
extern "C" void kernel_launch(void* const* d_in, const int* in_sizes, int n_in,
                              void* d_out, int out_size, void* d_ws, size_t ws_size,
                              hipStream_t stream)
{
    const float* cur  = (const float*)d_in[0];
    const float* ref  = (const float*)d_in[1];
    const float* Wq   = (const float*)d_in[2];
    const float* Wk   = (const float*)d_in[3];
    const float* Wv   = (const float*)d_in[4];
    const float* Wver = (const float*)d_in[5];
    const float* Whor = (const float*)d_in[6];
    float* out = (float*)d_out;

    float* ws = (float*)d_ws;
    const size_t NQ = 8 * 8 * (size_t)PLANE;   // 1,048,576 floats
    float* Q   = ws;
    float* K   = Q  + NQ;
    float* V   = K  + NQ;
    float* QT  = V  + NQ;
    float* KT  = QT + NQ;
    float* VT  = KT + NQ;
    float* OVT = VT + NQ;                      // [sb][w][h]
    float* OH  = OVT + 8 * (size_t)PLANE;      // [sb][h][w]

    qkv_kernel<<<1024, 512, 0, stream>>>(cur, ref, Wq, Wk, Wv, Q, K, V);
    transpose_kernel<<<1024, 256, 0, stream>>>(Q, K, V, QT, KT, VT);
    attn_fused<<<2048, 1024, 0, stream>>>(Q, K, V, QT, KT, VT,
                                          Whor, Wver, OH, OVT);
    warp_kernel<<<2048, 256, 0, stream>>>(ref, OVT, OH, out);
}

// Round 5
// 196.418 us; speedup vs baseline: 1.0177x; 1.0177x over previous
//
#include <hip/hip_runtime.h>

// CrossWarpingModule: 4-phase pixel-unshuffle -> axial attention (8 heads, c=1)
// -> flow -> bilinear border grid_sample -> pixel-shuffle back.
// B=2, C=64, H=W=256; sub-images: 8 x [64][128][128].
//
// R5: attn blocks shrunk 1024->256 threads (4 waves/block, 8 blocks/CU =
// 100% occupancy cap vs 50% before); each thread serially handles 4 heads.

constexpr int PLANE = 16384;                 // 128*128
constexpr float LOG2E = 1.4426950408889634f;

// ---------------------------------------------------------------------------
// Kernel 1: q/k/v projection. Block = (b, Y, X-half): 128 contiguous X
// positions x 4 channel-groups (16 ch each). Tree-reduce in LDS.
// grid 1024 x 512.
// ---------------------------------------------------------------------------
__global__ __launch_bounds__(512) void qkv_kernel(
    const float* __restrict__ cur, const float* __restrict__ ref,
    const float* __restrict__ Wq, const float* __restrict__ Wk,
    const float* __restrict__ Wv,
    float* __restrict__ Q, float* __restrict__ K, float* __restrict__ V)
{
    __shared__ float WT[64 * 24];       // WT[c][j]: j<8 Wq, <16 Wk, <24 Wv
    __shared__ float red0[128 * 25];    // stride 25: conflict-free
    __shared__ float red1[128 * 25];
    const int tid = threadIdx.x;
    for (int i = tid; i < 64 * 24; i += 512) {
        int c = i / 24, j = i % 24;
        float val = (j < 8) ? Wq[j * 64 + c]
                  : (j < 16) ? Wk[(j - 8) * 64 + c]
                  : Wv[(j - 16) * 64 + c];
        WT[c * 24 + j] = val;
    }
    __syncthreads();

    const int bi = blockIdx.x;               // 0..1023
    const int b  = bi >> 9;                  // batch
    const int Y  = (bi >> 1) & 255;          // full-res row
    const int Xh = bi & 1;                   // X half
    const int cg = tid >> 7;                 // channel group 0..3
    const int xi = tid & 127;
    const int X  = Xh * 128 + xi;            // full-res col (contiguous/lane)

    const size_t base_in = (size_t)b * 64 * 65536 + (size_t)Y * 256 + X;
    const float* curp = cur + base_in;
    const float* refp = ref + base_in;

    float q[8], k[8], v[8];
#pragma unroll
    for (int i = 0; i < 8; ++i) { q[i] = 0.f; k[i] = 0.f; v[i] = 0.f; }

    const int c0 = cg * 16;
#pragma unroll 8
    for (int c = 0; c < 16; ++c) {
        float cu = curp[(size_t)(c0 + c) * 65536];
        float rf = refp[(size_t)(c0 + c) * 65536];
        const float* wr = &WT[(c0 + c) * 24];
#pragma unroll
        for (int i = 0; i < 8; ++i) {
            q[i] = fmaf(wr[i],      cu, q[i]);
            k[i] = fmaf(wr[8 + i],  rf, k[i]);
            v[i] = fmaf(wr[16 + i], rf, v[i]);
        }
    }

    // tree reduce: (1 -> red0), (3 -> red1); (2 += red1); (0 += red0+red1)
    float* row0 = &red0[xi * 25];
    float* row1 = &red1[xi * 25];
    if (cg == 1) {
#pragma unroll
        for (int i = 0; i < 8; ++i) {
            row0[i] = q[i]; row0[8 + i] = k[i]; row0[16 + i] = v[i];
        }
    } else if (cg == 3) {
#pragma unroll
        for (int i = 0; i < 8; ++i) {
            row1[i] = q[i]; row1[8 + i] = k[i]; row1[16 + i] = v[i];
        }
    }
    __syncthreads();
    if (cg == 2) {
#pragma unroll
        for (int i = 0; i < 8; ++i) {
            row1[i]      += q[i];
            row1[8 + i]  += k[i];
            row1[16 + i] += v[i];
        }
    } else if (cg == 0) {
#pragma unroll
        for (int i = 0; i < 8; ++i) {
            q[i] += row0[i]; k[i] += row0[8 + i]; v[i] += row0[16 + i];
        }
    }
    __syncthreads();
    if (cg == 0) {
        const int dy = Y & 1, dx = X & 1;
        // (dy,dx)->phase: (0,0)=0 (1,1)=1 (0,1)=2 (1,0)=3
        const int p  = dy ? (dx ? 1 : 3) : (dx ? 2 : 0);
        const int sb = p * 2 + b;
        const int h = Y >> 1, w = X >> 1;
#pragma unroll
        for (int i = 0; i < 8; ++i) {
            const size_t o = ((size_t)(sb * 8 + i) << 14) + (h << 7) + w;
            Q[o] = q[i] + row1[i];
            K[o] = k[i] + row1[8 + i];
            V[o] = v[i] + row1[16 + i];
        }
    }
}

// ---------------------------------------------------------------------------
// Kernel 2: per-plane 128x128 transpose of Q,K,V -> QT,KT,VT. 32x32 LDS
// tiles, coalesced float4 on both sides. grid 1024 x 256.
// ---------------------------------------------------------------------------
__global__ __launch_bounds__(256) void transpose_kernel(
    const float* __restrict__ Q, const float* __restrict__ K,
    const float* __restrict__ V,
    float* __restrict__ QT, float* __restrict__ KT, float* __restrict__ VT)
{
    __shared__ float tile[32 * 33];
    const int bi = blockIdx.x;         // 0..1023
    const int plane = bi >> 4;         // (sb*8+head)
    const int ti = (bi >> 2) & 3, tj = bi & 3;
    const int t = threadIdx.x;
    const int r = t >> 3, c4 = (t & 7) * 4;     // 32 rows x 8 float4 cols
    const size_t pb = (size_t)plane << 14;
    const size_t ibase = pb + (size_t)(ti * 32) * 128 + tj * 32;
    const size_t obase = pb + (size_t)(tj * 32) * 128 + ti * 32;

    const float* srcs[3] = { Q, K, V };
    float* dsts[3] = { QT, KT, VT };
#pragma unroll
    for (int a = 0; a < 3; ++a) {
        const float* src = srcs[a];
        float* dst = dsts[a];
        const float4 val = *(const float4*)&src[ibase + (size_t)r * 128 + c4];
        if (a) __syncthreads();
        tile[r * 33 + c4 + 0] = val.x;
        tile[r * 33 + c4 + 1] = val.y;
        tile[r * 33 + c4 + 2] = val.z;
        tile[r * 33 + c4 + 3] = val.w;
        __syncthreads();
        float4 o;
        o.x = tile[(c4 + 0) * 33 + r];
        o.y = tile[(c4 + 1) * 33 + r];
        o.z = tile[(c4 + 2) * 33 + r];
        o.w = tile[(c4 + 3) * 33 + r];
        *(float4*)&dst[obase + (size_t)r * 128 + c4] = o;
    }
}

// ---------------------------------------------------------------------------
// Kernel 3: both axial attention passes + 8->1 head projection, fused.
// Block = (pass, sb, line), 256 threads = (sub = tid>>7, t = tid&127);
// each thread serially processes heads {sub*4 .. sub*4+3} (head wave-uniform
// within a wave -> LDS reads stay broadcast ds_read_b128).
// Block 0..1023:    horizontal (Q,K,V, Whor) -> OH[sb][h][w]   (line=h, t=w)
// Block 1024..2047: vertical  (QT,KT,VT,Wver) -> OVT[sb][w][h] (line=w, t=h)
// 4 accumulator pairs per head break the FP dependency chains.
// No max-subtract: |q·k| <~ 6, far inside exp2 range (matches ref, fp32).
// grid 2048 x 256. 4 waves/block, 8 blocks/CU -> 32 waves/CU.
// ---------------------------------------------------------------------------
__global__ __launch_bounds__(256) void attn_fused(
    const float* __restrict__ Q, const float* __restrict__ K,
    const float* __restrict__ V,
    const float* __restrict__ QT, const float* __restrict__ KT,
    const float* __restrict__ VT,
    const float* __restrict__ Whor, const float* __restrict__ Wver,
    float* __restrict__ OH, float* __restrict__ OVT)
{
    __shared__ float kk[8 * 128];   // [head][l], pre-scaled by log2(e)
    __shared__ float vv[8 * 128];
    __shared__ float red[8 * 128];  // per-head softmax results

    const int pass = blockIdx.x >> 10;
    const float* __restrict__ Qa = pass ? QT : Q;
    const float* __restrict__ Ka = pass ? KT : K;
    const float* __restrict__ Va = pass ? VT : V;
    const float* __restrict__ wsel = pass ? Wver : Whor;
    float* __restrict__ o = pass ? OVT : OH;

    const int tid  = threadIdx.x;
    const int sub  = tid >> 7;          // head group 0/1 (wave-uniform)
    const int t    = tid & 127;
    const int sbl  = blockIdx.x & 1023;
    const int sb   = sbl >> 7;
    const int line = sbl & 127;

    const size_t base = (((size_t)(sb * 8)) << 14) + ((size_t)line << 7);
    // stage all 8 heads' k,v rows (contiguous per head, head stride 16384)
#pragma unroll
    for (int i = 0; i < 4; ++i) {
        const int idx = i * 256 + tid;            // 0..1023
        const int hh = idx >> 7, tt = idx & 127;
        const size_t g = base + ((size_t)hh << 14) + tt;
        kk[idx] = LOG2E * Ka[g];
        vv[idx] = Va[g];
    }
    __syncthreads();

#pragma unroll
    for (int i = 0; i < 4; ++i) {
        const int head = sub * 4 + i;             // wave-uniform
        const float s = Qa[base + ((size_t)head << 14) + t];
        const float4* k4 = (const float4*)&kk[head << 7];
        const float4* v4 = (const float4*)&vv[head << 7];
        float d0 = 0.f, d1 = 0.f, d2 = 0.f, d3 = 0.f;
        float n0 = 0.f, n1 = 0.f, n2 = 0.f, n3 = 0.f;
#pragma unroll 8
        for (int l = 0; l < 32; ++l) {
            const float4 kq = k4[l];
            const float4 vq = v4[l];
            const float e0 = __builtin_amdgcn_exp2f(s * kq.x);
            const float e1 = __builtin_amdgcn_exp2f(s * kq.y);
            const float e2 = __builtin_amdgcn_exp2f(s * kq.z);
            const float e3 = __builtin_amdgcn_exp2f(s * kq.w);
            d0 += e0; n0 = fmaf(e0, vq.x, n0);
            d1 += e1; n1 = fmaf(e1, vq.y, n1);
            d2 += e2; n2 = fmaf(e2, vq.z, n2);
            d3 += e3; n3 = fmaf(e3, vq.w, n3);
        }
        const float den = (d0 + d1) + (d2 + d3);
        const float num = (n0 + n1) + (n2 + n3);
        red[(head << 7) + t] = num * __builtin_amdgcn_rcpf(den);
    }
    __syncthreads();

    if (tid < 128) {
        float acc = 0.f;
#pragma unroll
        for (int i = 0; i < 8; ++i)
            acc = fmaf(wsel[i], red[(i << 7) + tid], acc);
        o[((size_t)sb << 14) + ((size_t)line << 7) + tid] = acc;
    }
}

// ---------------------------------------------------------------------------
// Kernel 4: warp, output-major. Block = (b, cgroup, Y); lane = X. Phase from
// (Y&1, X&1) => stores are contiguous full-res rows (fully coalesced); the
// even/odd-lane union makes bilinear gathers near-contiguous (col ~ X+2*flow).
// Flow read once per pixel, reused over 16 channels. grid 2048 x 256.
// ---------------------------------------------------------------------------
__global__ __launch_bounds__(256) void warp_kernel(
    const float* __restrict__ ref, const float* __restrict__ ovt,
    const float* __restrict__ oh, float* __restrict__ out)
{
    const int bi = blockIdx.x;          // 0..2047
    const int Y  = bi & 255;
    const int cg = (bi >> 8) & 3;
    const int b  = bi >> 10;
    const int X  = threadIdx.x;

    const int dy = Y & 1, dx = X & 1;
    const int p  = dy ? (dx ? 1 : 3) : (dx ? 2 : 0);
    const int sb = p * 2 + b;
    const int h = Y >> 1, w = X >> 1;

    // normalized-coord round trip cancels exactly:
    const float ix = (float)w + oh [((size_t)sb << 14) + (h << 7) + w];
    const float iy = (float)h + ovt[((size_t)sb << 14) + (w << 7) + h];

    const float x0f = floorf(ix), y0f = floorf(iy);
    const float wx = ix - x0f,    wy = iy - y0f;
    const int x0 = (int)x0f, y0 = (int)y0f;
    const int x0c = min(max(x0, 0), 127),     x1c = min(max(x0 + 1, 0), 127);
    const int y0c = min(max(y0, 0), 127),     y1c = min(max(y0 + 1, 0), 127);

    const float w00 = (1.f - wx) * (1.f - wy);
    const float w01 = wx * (1.f - wy);
    const float w10 = (1.f - wx) * wy;
    const float w11 = wx * wy;

    const int r0 = (2 * y0c + dy) * 256, r1 = (2 * y1c + dy) * 256;
    const int c0 = 2 * x0c + dx,         c1 = 2 * x1c + dx;
    const int o00 = r0 + c0, o01 = r0 + c1, o10 = r1 + c0, o11 = r1 + c1;
    const int dst = Y * 256 + X;

    const float* rp = ref + ((size_t)b * 64 + cg * 16) * 65536;
    float* op = out + ((size_t)b * 64 + cg * 16) * 65536;

#pragma unroll 4
    for (int c = 0; c < 16; ++c) {
        const size_t pl = (size_t)c * 65536;
        const float v00 = rp[pl + o00], v01 = rp[pl + o01];
        const float v10 = rp[pl + o10], v11 = rp[pl + o11];
        op[pl + dst] = fmaf(w00, v00, fmaf(w01, v01, fmaf(w10, v10, w11 * v11)));
    }
}

// ---------------------------------------------------------------------------
extern "C" void kernel_launch(void* const* d_in, const int* in_sizes, int n_in,
                              void* d_out, int out_size, void* d_ws, size_t ws_size,
                              hipStream_t stream)
{
    const float* cur  = (const float*)d_in[0];
    const float* ref  = (const float*)d_in[1];
    const float* Wq   = (const float*)d_in[2];
    const float* Wk   = (const float*)d_in[3];
    const float* Wv   = (const float*)d_in[4];
    const float* Wver = (const float*)d_in[5];
    const float* Whor = (const float*)d_in[6];
    float* out = (float*)d_out;

    float* ws = (float*)d_ws;
    const size_t NQ = 8 * 8 * (size_t)PLANE;   // 1,048,576 floats
    float* Q   = ws;
    float* K   = Q  + NQ;
    float* V   = K  + NQ;
    float* QT  = V  + NQ;
    float* KT  = QT + NQ;
    float* VT  = KT + NQ;
    float* OVT = VT + NQ;                      // [sb][w][h]
    float* OH  = OVT + 8 * (size_t)PLANE;      // [sb][h][w]

    qkv_kernel<<<1024, 512, 0, stream>>>(cur, ref, Wq, Wk, Wv, Q, K, V);
    transpose_kernel<<<1024, 256, 0, stream>>>(Q, K, V, QT, KT, VT);
    attn_fused<<<2048, 256, 0, stream>>>(Q, K, V, QT, KT, VT,
                                         Whor, Wver, OH, OVT);
    warp_kernel<<<2048, 256, 0, stream>>>(ref, OVT, OH, out);
}

// Round 7
// 186.243 us; speedup vs baseline: 1.0733x; 1.0546x over previous
//
#include <hip/hip_runtime.h>

// CrossWarpingModule: 4-phase pixel-unshuffle -> axial attention (8 heads, c=1)
// -> flow -> bilinear border grid_sample -> pixel-shuffle back.
// B=2, C=64, H=W=256; sub-images: 8 x [64][128][128].
//
// R7 = R6 with the attn staging overflow fixed (256 float4s, single pass).
// attn: LOG2E pre-folded into Wk (qkv), float4 staging, packed float2
// accumulators, slim 2-partial epilogue. warp: x-tap pair fetched as one
// float4 per row (VMEM halved), cndmask tap select with border handling.

constexpr int PLANE = 16384;                 // 128*128
constexpr float LOG2E = 1.4426950408889634f;

typedef float v2f __attribute__((ext_vector_type(2)));

// ---------------------------------------------------------------------------
// Kernel 1: q/k/v projection. Block = (b, Y, X-half): 128 contiguous X
// positions x 4 channel-groups (16 ch each). Tree-reduce in LDS.
// K is written pre-scaled by log2(e) (consumed only via exp2 in attn).
// grid 1024 x 512.
// ---------------------------------------------------------------------------
__global__ __launch_bounds__(512) void qkv_kernel(
    const float* __restrict__ cur, const float* __restrict__ ref,
    const float* __restrict__ Wq, const float* __restrict__ Wk,
    const float* __restrict__ Wv,
    float* __restrict__ Q, float* __restrict__ K, float* __restrict__ V)
{
    __shared__ float WT[64 * 24];       // WT[c][j]: j<8 Wq, <16 Wk*log2e, <24 Wv
    __shared__ float red0[128 * 25];    // stride 25: conflict-free
    __shared__ float red1[128 * 25];
    const int tid = threadIdx.x;
    for (int i = tid; i < 64 * 24; i += 512) {
        int c = i / 24, j = i % 24;
        float val = (j < 8) ? Wq[j * 64 + c]
                  : (j < 16) ? LOG2E * Wk[(j - 8) * 64 + c]
                  : Wv[(j - 16) * 64 + c];
        WT[c * 24 + j] = val;
    }
    __syncthreads();

    const int bi = blockIdx.x;               // 0..1023
    const int b  = bi >> 9;                  // batch
    const int Y  = (bi >> 1) & 255;          // full-res row
    const int Xh = bi & 1;                   // X half
    const int cg = tid >> 7;                 // channel group 0..3
    const int xi = tid & 127;
    const int X  = Xh * 128 + xi;            // full-res col (contiguous/lane)

    const size_t base_in = (size_t)b * 64 * 65536 + (size_t)Y * 256 + X;
    const float* curp = cur + base_in;
    const float* refp = ref + base_in;

    float q[8], k[8], v[8];
#pragma unroll
    for (int i = 0; i < 8; ++i) { q[i] = 0.f; k[i] = 0.f; v[i] = 0.f; }

    const int c0 = cg * 16;
#pragma unroll 8
    for (int c = 0; c < 16; ++c) {
        float cu = curp[(size_t)(c0 + c) * 65536];
        float rf = refp[(size_t)(c0 + c) * 65536];
        const float* wr = &WT[(c0 + c) * 24];
#pragma unroll
        for (int i = 0; i < 8; ++i) {
            q[i] = fmaf(wr[i],      cu, q[i]);
            k[i] = fmaf(wr[8 + i],  rf, k[i]);
            v[i] = fmaf(wr[16 + i], rf, v[i]);
        }
    }

    // tree reduce: (1 -> red0), (3 -> red1); (2 += red1); (0 += red0+red1)
    float* row0 = &red0[xi * 25];
    float* row1 = &red1[xi * 25];
    if (cg == 1) {
#pragma unroll
        for (int i = 0; i < 8; ++i) {
            row0[i] = q[i]; row0[8 + i] = k[i]; row0[16 + i] = v[i];
        }
    } else if (cg == 3) {
#pragma unroll
        for (int i = 0; i < 8; ++i) {
            row1[i] = q[i]; row1[8 + i] = k[i]; row1[16 + i] = v[i];
        }
    }
    __syncthreads();
    if (cg == 2) {
#pragma unroll
        for (int i = 0; i < 8; ++i) {
            row1[i]      += q[i];
            row1[8 + i]  += k[i];
            row1[16 + i] += v[i];
        }
    } else if (cg == 0) {
#pragma unroll
        for (int i = 0; i < 8; ++i) {
            q[i] += row0[i]; k[i] += row0[8 + i]; v[i] += row0[16 + i];
        }
    }
    __syncthreads();
    if (cg == 0) {
        const int dy = Y & 1, dx = X & 1;
        // (dy,dx)->phase: (0,0)=0 (1,1)=1 (0,1)=2 (1,0)=3
        const int p  = dy ? (dx ? 1 : 3) : (dx ? 2 : 0);
        const int sb = p * 2 + b;
        const int h = Y >> 1, w = X >> 1;
#pragma unroll
        for (int i = 0; i < 8; ++i) {
            const size_t o = ((size_t)(sb * 8 + i) << 14) + (h << 7) + w;
            Q[o] = q[i] + row1[i];
            K[o] = k[i] + row1[8 + i];
            V[o] = v[i] + row1[16 + i];
        }
    }
}

// ---------------------------------------------------------------------------
// Kernel 2: per-plane 128x128 transpose of Q,K,V -> QT,KT,VT. 32x32 LDS
// tiles, coalesced float4 on both sides. grid 1024 x 256.
// ---------------------------------------------------------------------------
__global__ __launch_bounds__(256) void transpose_kernel(
    const float* __restrict__ Q, const float* __restrict__ K,
    const float* __restrict__ V,
    float* __restrict__ QT, float* __restrict__ KT, float* __restrict__ VT)
{
    __shared__ float tile[32 * 33];
    const int bi = blockIdx.x;         // 0..1023
    const int plane = bi >> 4;         // (sb*8+head)
    const int ti = (bi >> 2) & 3, tj = bi & 3;
    const int t = threadIdx.x;
    const int r = t >> 3, c4 = (t & 7) * 4;     // 32 rows x 8 float4 cols
    const size_t pb = (size_t)plane << 14;
    const size_t ibase = pb + (size_t)(ti * 32) * 128 + tj * 32;
    const size_t obase = pb + (size_t)(tj * 32) * 128 + ti * 32;

    const float* srcs[3] = { Q, K, V };
    float* dsts[3] = { QT, KT, VT };
#pragma unroll
    for (int a = 0; a < 3; ++a) {
        const float* src = srcs[a];
        float* dst = dsts[a];
        const float4 val = *(const float4*)&src[ibase + (size_t)r * 128 + c4];
        if (a) __syncthreads();
        tile[r * 33 + c4 + 0] = val.x;
        tile[r * 33 + c4 + 1] = val.y;
        tile[r * 33 + c4 + 2] = val.z;
        tile[r * 33 + c4 + 3] = val.w;
        __syncthreads();
        float4 o;
        o.x = tile[(c4 + 0) * 33 + r];
        o.y = tile[(c4 + 1) * 33 + r];
        o.z = tile[(c4 + 2) * 33 + r];
        o.w = tile[(c4 + 3) * 33 + r];
        *(float4*)&dst[obase + (size_t)r * 128 + c4] = o;
    }
}

// ---------------------------------------------------------------------------
// Kernel 3: both axial attention passes + 8->1 head projection, fused.
// Block = (pass, sb, line), 256 threads = (sub = tid>>7, t = tid&127);
// thread handles heads {sub*4..sub*4+3}; head wave-uniform -> LDS reads are
// broadcast ds_read_b128. K already pre-scaled by log2e. Packed float2
// accumulators. Epilogue: 2-partial weighted-sum add.
// Staging: kk/vv are 256 float4s each -> exactly one float4 per thread.
// grid 2048 x 256.
// ---------------------------------------------------------------------------
__global__ __launch_bounds__(256) void attn_fused(
    const float* __restrict__ Q, const float* __restrict__ K,
    const float* __restrict__ V,
    const float* __restrict__ QT, const float* __restrict__ KT,
    const float* __restrict__ VT,
    const float* __restrict__ Whor, const float* __restrict__ Wver,
    float* __restrict__ OH, float* __restrict__ OVT)
{
    __shared__ __align__(16) float kk[8 * 128];   // pre-scaled by log2(e)
    __shared__ __align__(16) float vv[8 * 128];
    __shared__ float part[128];                   // sub=1 partial sums

    const int pass = blockIdx.x >> 10;
    const float* __restrict__ Qa = pass ? QT : Q;
    const float* __restrict__ Ka = pass ? KT : K;
    const float* __restrict__ Va = pass ? VT : V;
    const float* __restrict__ wsel = pass ? Wver : Whor;
    float* __restrict__ o = pass ? OVT : OH;

    const int tid  = threadIdx.x;
    const int sub  = tid >> 7;          // head group 0/1 (wave-uniform)
    const int t    = tid & 127;
    const int sbl  = blockIdx.x & 1023;
    const int sb   = sbl >> 7;
    const int line = sbl & 127;

    const size_t base = (((size_t)(sb * 8)) << 14) + ((size_t)line << 7);
    // stage all 8 heads' k,v rows: 256 float4s per array, one per thread.
    {
        const int f  = tid;                       // float4 id, 0..255
        const int hh = f >> 5;                    // head 0..7
        const int tt = (f & 31) << 2;             // element 0..124
        const size_t g = base + ((size_t)hh << 14) + tt;
        ((float4*)kk)[f] = *(const float4*)&Ka[g];
        ((float4*)vv)[f] = *(const float4*)&Va[g];
    }
    __syncthreads();

    float acc = 0.f;
#pragma unroll
    for (int i = 0; i < 4; ++i) {
        const int head = sub * 4 + i;             // wave-uniform
        const float s = Qa[base + ((size_t)head << 14) + t];
        const float4* k4 = (const float4*)&kk[head << 7];
        const float4* v4 = (const float4*)&vv[head << 7];
        v2f d01 = {0.f, 0.f}, d23 = {0.f, 0.f};
        v2f n01 = {0.f, 0.f}, n23 = {0.f, 0.f};
#pragma unroll 8
        for (int l = 0; l < 32; ++l) {
            const float4 kq = k4[l];
            const float4 vq = v4[l];
            v2f a01 = {s * kq.x, s * kq.y};
            v2f a23 = {s * kq.z, s * kq.w};
            v2f e01 = {__builtin_amdgcn_exp2f(a01.x), __builtin_amdgcn_exp2f(a01.y)};
            v2f e23 = {__builtin_amdgcn_exp2f(a23.x), __builtin_amdgcn_exp2f(a23.y)};
            d01 += e01;
            d23 += e23;
            n01 += e01 * (v2f){vq.x, vq.y};
            n23 += e23 * (v2f){vq.z, vq.w};
        }
        const v2f dv = d01 + d23, nv = n01 + n23;
        const float den = dv.x + dv.y;
        const float num = nv.x + nv.y;
        acc = fmaf(wsel[head], num * __builtin_amdgcn_rcpf(den), acc);
    }

    if (sub) part[t] = acc;
    __syncthreads();
    if (!sub) {
        o[((size_t)sb << 14) + ((size_t)line << 7) + t] = acc + part[t];
    }
}

// ---------------------------------------------------------------------------
// Kernel 4: warp, output-major. Block = (b, cgroup, Y); lane = X. Stores are
// contiguous full-res rows. Both x-taps (cols 2*x0c+dx, 2*x1c+dx) fetched as
// ONE float4 per row at col base cb=min(2*x0c,252) -> 2 dwordx4 per channel
// instead of 4 scalar loads; taps picked with cndmask (hi/up1 select covers
// border clamp). grid 2048 x 256.
// ---------------------------------------------------------------------------
__global__ __launch_bounds__(256) void warp_kernel(
    const float* __restrict__ ref, const float* __restrict__ ovt,
    const float* __restrict__ oh, float* __restrict__ out)
{
    const int bi = blockIdx.x;          // 0..2047
    const int Y  = bi & 255;
    const int cg = (bi >> 8) & 3;
    const int b  = bi >> 10;
    const int X  = threadIdx.x;

    const int dy = Y & 1, dx = X & 1;
    const int p  = dy ? (dx ? 1 : 3) : (dx ? 2 : 0);
    const int sb = p * 2 + b;
    const int h = Y >> 1, w = X >> 1;

    // normalized-coord round trip cancels exactly:
    const float ix = (float)w + oh [((size_t)sb << 14) + (h << 7) + w];
    const float iy = (float)h + ovt[((size_t)sb << 14) + (w << 7) + h];

    const float x0f = floorf(ix), y0f = floorf(iy);
    const float wx = ix - x0f,    wy = iy - y0f;
    const int x0 = (int)x0f, y0 = (int)y0f;
    const int x0c = min(max(x0, 0), 127),     x1c = min(max(x0 + 1, 0), 127);
    const int y0c = min(max(y0, 0), 127),     y1c = min(max(y0 + 1, 0), 127);

    const float w00 = (1.f - wx) * (1.f - wy);
    const float w01 = wx * (1.f - wy);
    const float w10 = (1.f - wx) * wy;
    const float w11 = wx * wy;

    const int cb  = min(2 * x0c, 252);      // float4 col base (8B-aligned ok)
    const bool hi  = (x0c == 127);          // taps live in upper half of f4
    const bool up1 = hi | (x1c != x0c);     // second tap uses upper element
    const int r0 = (2 * y0c + dy) * 256, r1 = (2 * y1c + dy) * 256;
    const int dst = Y * 256 + X;

    const float* rp = ref + ((size_t)b * 64 + cg * 16) * 65536;
    float* op = out + ((size_t)b * 64 + cg * 16) * 65536;

#pragma unroll 4
    for (int c = 0; c < 16; ++c) {
        const size_t pl = (size_t)c * 65536;
        const float4 f0 = *(const float4*)&rp[pl + r0 + cb];
        const float4 f1 = *(const float4*)&rp[pl + r1 + cb];
        const float L0 = dx ? f0.y : f0.x, H0 = dx ? f0.w : f0.z;
        const float L1 = dx ? f1.y : f1.x, H1 = dx ? f1.w : f1.z;
        const float v00 = hi ? H0 : L0,  v01 = up1 ? H0 : L0;
        const float v10 = hi ? H1 : L1,  v11 = up1 ? H1 : L1;
        op[pl + dst] = fmaf(w00, v00, fmaf(w01, v01, fmaf(w10, v10, w11 * v11)));
    }
}

// ---------------------------------------------------------------------------
extern "C" void kernel_launch(void* const* d_in, const int* in_sizes, int n_in,
                              void* d_out, int out_size, void* d_ws, size_t ws_size,
                              hipStream_t stream)
{
    const float* cur  = (const float*)d_in[0];
    const float* ref  = (const float*)d_in[1];
    const float* Wq   = (const float*)d_in[2];
    const float* Wk   = (const float*)d_in[3];
    const float* Wv   = (const float*)d_in[4];
    const float* Wver = (const float*)d_in[5];
    const float* Whor = (const float*)d_in[6];
    float* out = (float*)d_out;

    float* ws = (float*)d_ws;
    const size_t NQ = 8 * 8 * (size_t)PLANE;   // 1,048,576 floats
    float* Q   = ws;
    float* K   = Q  + NQ;                      // pre-scaled by log2(e)
    float* V   = K  + NQ;
    float* QT  = V  + NQ;
    float* KT  = QT + NQ;
    float* VT  = KT + NQ;
    float* OVT = VT + NQ;                      // [sb][w][h]
    float* OH  = OVT + 8 * (size_t)PLANE;      // [sb][h][w]

    qkv_kernel<<<1024, 512, 0, stream>>>(cur, ref, Wq, Wk, Wv, Q, K, V);
    transpose_kernel<<<1024, 256, 0, stream>>>(Q, K, V, QT, KT, VT);
    attn_fused<<<2048, 256, 0, stream>>>(Q, K, V, QT, KT, VT,
                                         Whor, Wver, OH, OVT);
    warp_kernel<<<2048, 256, 0, stream>>>(ref, OVT, OH, out);
}